// Round 2
// baseline (563.422 us; speedup 1.0000x reference)
//
#include <hip/hip_runtime.h>

// out[b,h,w,i,c] = inputs[b,h,w,i] * u[i,c],  u = beta^2 / rowsum(beta^2)
// B=8 H=128 W=128 D=64 C=16. Output 512 MiB fp32 -> write-BW bound.
// v3: 2-deep software pipeline. Loads for body j+2 are issued BEFORE stores of
//     body j, so the s_waitcnt guarding store data is vmcnt(~32) and never
//     forces prior stores to retire (in-order vmcnt would otherwise serialize
//     each body on store-ack latency -> the ~2.7 TB/s wall seen in v1/v2).

#define Dd 64
#define Cc 16
#define UNR 8

__global__ __launch_bounds__(256) void DS2_62466004353281_kernel(
    const float* __restrict__ inputs,   // [B*H*W*D] = 8388608
    const float* __restrict__ beta,     // [D*C] = 1024
    float* __restrict__ out,            // [B*H*W*D*C] = 134217728
    int n_quads)                        // out float4 count = 33554432
{
    __shared__ float u[Dd * Cc];        // 4 KiB normalized squared weights
    const int t = threadIdx.x;

    // threads 0..63 each compute one row of u
    if (t < Dd) {
        float b2[Cc];
        float s = 0.f;
#pragma unroll
        for (int c = 0; c < Cc; ++c) {
            float b = beta[t * Cc + c];
            b2[c] = b * b;
            s += b2[c];
        }
        float inv = 1.0f / s;
#pragma unroll
        for (int c = 0; c < Cc; ++c) u[t * Cc + c] = b2[c] * inv;
    }
    __syncthreads();

    const float4* __restrict__ u4 = (const float4*)u;
    float4* __restrict__ out4 = (float4*)out;

    const int stride  = gridDim.x * blockDim.x;   // quads per pass (mult of 256)
    const int estride = stride >> 2;              // input elems per pass
    const int base    = blockIdx.x * blockDim.x + t;

    // (i,q) invariant across grid-stride iterations -> read u fragment ONCE.
    const float4 uu = u4[(((base >> 2) & (Dd - 1)) << 2) | (base & 3)];

    // fixed problem size: n_quads = 64 * stride exactly -> pipelined path
    if ((n_quads % stride) == 0 && ((n_quads / stride) % UNR) == 0 &&
        (n_quads / stride) >= 2 * UNR) {
        const int nb = (n_quads / stride) / UNR;  // unroll bodies (8)

        float x0[UNR], x1[UNR];
        int le   = base >> 2;                     // load elem cursor
        int sidx = base;                          // store quad cursor

        // prologue: issue loads for bodies 0 and 1
#pragma unroll
        for (int k = 0; k < UNR; ++k) x0[k] = inputs[le + k * estride];
        le += UNR * estride;
#pragma unroll
        for (int k = 0; k < UNR; ++k) x1[k] = inputs[le + k * estride];
        le += UNR * estride;

        // steady state: issue loads for body b+2, then store body b.
        // Load->use distance = 2 bodies => waits tolerate ~2 bodies of
        // outstanding stores (no store-retirement serialization).
        for (int b = 0; b < nb - 2; ++b) {
            float xn[UNR];
#pragma unroll
            for (int k = 0; k < UNR; ++k) xn[k] = inputs[le + k * estride];
            le += UNR * estride;

#pragma unroll
            for (int k = 0; k < UNR; ++k) {
                const float x = x0[k];
                float4 o;
                o.x = x * uu.x; o.y = x * uu.y; o.z = x * uu.z; o.w = x * uu.w;
                out4[sidx + k * stride] = o;
            }
            sidx += UNR * stride;

#pragma unroll
            for (int k = 0; k < UNR; ++k) { x0[k] = x1[k]; x1[k] = xn[k]; }
        }

        // epilogue: store the last two bodies
#pragma unroll
        for (int k = 0; k < UNR; ++k) {
            const float x = x0[k];
            float4 o;
            o.x = x * uu.x; o.y = x * uu.y; o.z = x * uu.z; o.w = x * uu.w;
            out4[sidx + k * stride] = o;
        }
        sidx += UNR * stride;
#pragma unroll
        for (int k = 0; k < UNR; ++k) {
            const float x = x1[k];
            float4 o;
            o.x = x * uu.x; o.y = x * uu.y; o.z = x * uu.z; o.w = x * uu.w;
            out4[sidx + k * stride] = o;
        }
    } else {
        // generic fallback (not taken at the fixed problem size)
        for (int idx = base; idx < n_quads; idx += stride) {
            const float x = inputs[idx >> 2];
            float4 o;
            o.x = x * uu.x; o.y = x * uu.y; o.z = x * uu.z; o.w = x * uu.w;
            out4[idx] = o;
        }
    }
}

extern "C" void kernel_launch(void* const* d_in, const int* in_sizes, int n_in,
                              void* d_out, int out_size, void* d_ws, size_t ws_size,
                              hipStream_t stream) {
    const float* inputs = (const float*)d_in[0];
    const float* beta   = (const float*)d_in[1];
    float* out          = (float*)d_out;

    const int n_quads = out_size / 4;   // 33,554,432 float4 stores
    // 2048 blocks = 8 blocks/CU fully resident; 64 grid-stride iters/thread.
    dim3 grid(2048), block(256);
    DS2_62466004353281_kernel<<<grid, block, 0, stream>>>(inputs, beta, out, n_quads);
}